// Round 7
// baseline (298.139 us; speedup 1.0000x reference)
//
#include <hip/hip_runtime.h>

#define B_    128
#define I_    4608
#define O_    10
#define D_    16
#define NCHUNKS 2304      // I_/2
#define NIB   64          // i-blocks; 72 i = 36 chunks each
#define CPB   36          // chunks per i-block
#define CHH   5120        // halves per prepped chunk: 2 img * 5 p * 64 lane * 8
#define PSET  20480       // floats per partial set (128*10*16)
#define NBLKS 256

typedef _Float16 f16x2 __attribute__((ext_vector_type(2)));
typedef _Float16 f16x4 __attribute__((ext_vector_type(4)));
typedef _Float16 f16x8 __attribute__((ext_vector_type(8)));
typedef float    f32x4 __attribute__((ext_vector_type(4)));
typedef __fp16   pk16x2 __attribute__((ext_vector_type(2)));
typedef unsigned int uint2v __attribute__((ext_vector_type(2)));

__device__ __forceinline__ f16x4 pack4(float a, float b, float c, float d) {
    union { f16x4 v; pk16x2 p[2]; } u;
    u.p[0] = __builtin_amdgcn_cvt_pkrtz(a, b);
    u.p[1] = __builtin_amdgcn_cvt_pkrtz(c, d);
    return u.v;
}
__device__ __forceinline__ f16x2 splat_h2(float a) {
    union { f16x2 v; pk16x2 p; } u;
    u.p = __builtin_amdgcn_cvt_pkrtz(a, a);
    return u.v;
}

// ---- sense-free grid barrier (generation counter, device scope) ----
__device__ __forceinline__ void gbar(unsigned* cnt, unsigned* gen) {
    __syncthreads();
    if (threadIdx.x == 0) {
        const unsigned g = __hip_atomic_load(gen, __ATOMIC_RELAXED, __HIP_MEMORY_SCOPE_AGENT);
        __threadfence();   // release our writes
        const unsigned a = __hip_atomic_fetch_add(cnt, 1u, __ATOMIC_ACQ_REL, __HIP_MEMORY_SCOPE_AGENT);
        if (a == NBLKS - 1u) {
            __hip_atomic_store(cnt, 0u, __ATOMIC_RELAXED, __HIP_MEMORY_SCOPE_AGENT);
            __hip_atomic_fetch_add(gen, 1u, __ATOMIC_RELEASE, __HIP_MEMORY_SCOPE_AGENT);
        } else {
            while (__hip_atomic_load(gen, __ATOMIC_ACQUIRE, __HIP_MEMORY_SCOPE_AGENT) == g)
                __builtin_amdgcn_s_sleep(2);
        }
        __threadfence();   // acquire: invalidate before reading others' data
    }
    __syncthreads();
}

// ---------------------------------------------------------------------------
// Pass phase (R6-verified logic). Wave-independent chunks, frags direct from
// global. MODE 0: uniform c. Tree-reduce over waves into parts[ib].
// ---------------------------------------------------------------------------
template<int MODE>
__device__ __forceinline__ void pass_phase(
    const float* __restrict__ x, const _Float16* __restrict__ pw,
    const float* __restrict__ v, float* __restrict__ parts,
    float* red, int lane, int wv, int bl, int g, int ib, int bg)
{
    const int c0   = ib * CPB;
    const int cend = c0 + CPB;
    const int iloc = g & 1, kq = g >> 1;
    const int b0   = bg * 32 + bl;

    f16x4 vf[2][O_];
    if (MODE == 1) {
#pragma unroll
        for (int tile = 0; tile < 2; ++tile)
#pragma unroll
            for (int o = 0; o < O_; ++o) {
                const float4 vv = *(const float4*)(v + ((long)(b0 + tile * 16) * O_ + o) * D_ + g * 4);
                vf[tile][o] = pack4(vv.x, vv.y, vv.z, vv.w);
            }
    }

    f32x4 S[2][O_];
#pragma unroll
    for (int tile = 0; tile < 2; ++tile)
#pragma unroll
        for (int o = 0; o < O_; ++o) S[tile][o] = (f32x4)(0.f);

    const long lofs = (long)lane * 8;
    auto fragp = [&](int c, int img, int p) {
        return (const f16x8*)(pw + (long)c * CHH + img * 2560 + p * 512 + lofs);
    };
    auto xp = [&](int c, int tile) {
        return (const float4*)(x + ((long)(b0 + tile * 16) * I_ + 2 * c + iloc) * 8 + kq * 4);
    };

    int c = c0 + wv;
    f16x8 f0[5], f1[5];
    float4 xqC[2], xqN[2];
    if (MODE == 1) {
#pragma unroll
        for (int p = 0; p < 5; ++p) f0[p] = *fragp(c, 0, p);
    }
#pragma unroll
    for (int p = 0; p < 5; ++p) f1[p] = *fragp(c, 1, p);
    xqC[0] = *xp(c, 0); xqC[1] = *xp(c, 1);

#pragma unroll
    for (int t5 = 0; t5 < 5; ++t5) {
        const bool valid = (c < cend);
        int cn = c + 8; if (cn > NCHUNKS - 1) cn = NCHUNKS - 1;
        if (valid) {
            xqN[0] = *xp(cn, 0); xqN[1] = *xp(cn, 1);

            float cs[2][O_];
            if (MODE == 1) {
#pragma unroll
                for (int tile = 0; tile < 2; ++tile)
#pragma unroll
                    for (int p = 0; p < 5; ++p) {
                        f16x4 ae, ao;
                        ae[0]=f0[p][0]; ae[1]=f0[p][1]; ae[2]=f0[p][2]; ae[3]=f0[p][3];
                        ao[0]=f0[p][4]; ao[1]=f0[p][5]; ao[2]=f0[p][6]; ao[3]=f0[p][7];
                        const f32x4 ua = __builtin_amdgcn_mfma_f32_16x16x16f16(ae, vf[tile][2*p],   (f32x4)(0.f), 0, 0, 0);
                        const f32x4 ub = __builtin_amdgcn_mfma_f32_16x16x16f16(ao, vf[tile][2*p+1], (f32x4)(0.f), 0, 0, 0);
                        const float4 xq = xqC[tile];
                        float d0 = ua[0] * xq.x; d0 = fmaf(ua[1], xq.y, d0);
                        d0 = fmaf(ua[2], xq.z, d0); d0 = fmaf(ua[3], xq.w, d0);
                        float d1 = ub[0] * xq.x; d1 = fmaf(ub[1], xq.y, d1);
                        d1 = fmaf(ub[2], xq.z, d1); d1 = fmaf(ub[3], xq.w, d1);
                        cs[tile][2*p] = d0; cs[tile][2*p+1] = d1;
                    }
#pragma unroll
                for (int p = 0; p < 5; ++p) f0[p] = *fragp(cn, 0, p);
#pragma unroll
                for (int tile = 0; tile < 2; ++tile) {
                    float ssum = 0.f;
#pragma unroll
                    for (int o = 0; o < O_; ++o) {
                        const unsigned int tt = __float_as_uint(cs[tile][o]);
                        const uint2v sw = __builtin_amdgcn_permlane32_swap(tt, tt, false, false);
                        const float e = __expf(__uint_as_float(sw[0]) + __uint_as_float(sw[1]));
                        cs[tile][o] = e; ssum += e;
                    }
                    const float inv = 1.f / ssum;
#pragma unroll
                    for (int o = 0; o < O_; ++o) cs[tile][o] *= inv;
                }
            }

            union F4 { f16x4 v; f16x2 h[2]; };
            F4 xh[2];
            xh[0].v = pack4(xqC[0].x, xqC[0].y, xqC[0].z, xqC[0].w);
            xh[1].v = pack4(xqC[1].x, xqC[1].y, xqC[1].z, xqC[1].w);
#pragma unroll
            for (int p = 0; p < 5; ++p) {
                f16x4 pe, po;
                pe[0]=f1[p][0]; pe[1]=f1[p][1]; pe[2]=f1[p][2]; pe[3]=f1[p][3];
                po[0]=f1[p][4]; po[1]=f1[p][5]; po[2]=f1[p][6]; po[3]=f1[p][7];
#pragma unroll
                for (int tile = 0; tile < 2; ++tile) {
                    F4 ye, yo;
                    if (MODE == 0) { ye = xh[tile]; yo = xh[tile]; }
                    else {
                        const f16x2 ce = splat_h2(cs[tile][2*p]);
                        const f16x2 co = splat_h2(cs[tile][2*p+1]);
                        ye.h[0] = xh[tile].h[0] * ce; ye.h[1] = xh[tile].h[1] * ce;
                        yo.h[0] = xh[tile].h[0] * co; yo.h[1] = xh[tile].h[1] * co;
                    }
                    S[tile][2*p]   = __builtin_amdgcn_mfma_f32_16x16x16f16(pe, ye.v, S[tile][2*p],   0, 0, 0);
                    S[tile][2*p+1] = __builtin_amdgcn_mfma_f32_16x16x16f16(po, yo.v, S[tile][2*p+1], 0, 0, 0);
                }
            }
#pragma unroll
            for (int p = 0; p < 5; ++p) f1[p] = *fragp(cn, 1, p);
            xqC[0] = xqN[0]; xqC[1] = xqN[1];
        }
        c += 8;
    }

    // ---- inter-wave tree reduction ----
    auto slot = [&](int w, int tile, int o) {
        return &red[w * 5120 + (tile * O_ + o) * 256 + lane * 4];
    };
#define TREE_WR(WSRC)                                                       \
    if (wv >= WSRC) {                                                       \
        _Pragma("unroll") for (int tile = 0; tile < 2; ++tile)              \
        _Pragma("unroll") for (int o = 0; o < O_; ++o)                      \
            *(f32x4*)slot(wv - WSRC, tile, o) = S[tile][o];                 \
    }                                                                       \
    __syncthreads();                                                        \
    if (wv < WSRC) {                                                        \
        _Pragma("unroll") for (int tile = 0; tile < 2; ++tile)              \
        _Pragma("unroll") for (int o = 0; o < O_; ++o)                      \
            S[tile][o] += *(f32x4*)slot(wv, tile, o);                       \
    }                                                                       \
    __syncthreads();

    TREE_WR(4)
    TREE_WR(2)
    TREE_WR(1)
#undef TREE_WR

    if (wv == 0) {
#pragma unroll
        for (int tile = 0; tile < 2; ++tile)
#pragma unroll
            for (int o = 0; o < O_; ++o) {
                float* pp = parts + (long)ib * PSET
                          + ((long)(b0 + tile * 16) * O_ + o) * D_ + g * 4;
                *(f32x4*)pp = S[tile][o];
            }
    }
}

// ---------------------------------------------------------------------------
// Reduce phase: block u handles units [5u,5u+5) = (b*O+o); wave wv<5 each.
// ---------------------------------------------------------------------------
__device__ __forceinline__ void reduce_phase(
    const float* __restrict__ parts, float* __restrict__ v_buf,
    float* __restrict__ out, float kscale, float pre, int mode,
    int u, int lane, int wv)
{
    if (wv < 5) {
        const int unit = u * 5 + wv;
        const int pg = lane >> 4, d = lane & 15;
        float s = 0.f;
#pragma unroll
        for (int k = 0; k < 16; ++k)
            s += parts[(long)(pg * 16 + k) * PSET + unit * D_ + d];
        s += __shfl_xor(s, 16);
        s += __shfl_xor(s, 32);
        s *= pre;
        float n2 = s * s;
        n2 += __shfl_xor(n2, 1);
        n2 += __shfl_xor(n2, 2);
        n2 += __shfl_xor(n2, 4);
        n2 += __shfl_xor(n2, 8);
        if (lane < 16) {
            const float n     = sqrtf(n2);
            const float scale = n2 / ((1.f + n2) * (n + 1e-8f));
            const float o_    = scale * s;
            const int idx = unit * D_ + lane;
            if (mode == 0)      { v_buf[idx] = o_;  out[idx]  = kscale * o_; }
            else if (mode == 1) { v_buf[idx] += o_; out[idx] += kscale * o_; }
            else                {                   out[idx] += kscale * o_; }
        }
    }
}

// ---------------------------------------------------------------------------
// Persistent fused kernel: prep | p0 | r0 | p1 | r1 | p2 | r2, 6 grid barriers.
// ---------------------------------------------------------------------------
__global__ __launch_bounds__(512, 2)
void cap_kernel(const float* __restrict__ x, const float* __restrict__ w,
                float* __restrict__ parts, float* __restrict__ v_buf,
                float* __restrict__ out, _Float16* __restrict__ pw,
                unsigned* __restrict__ bar)
{
    __shared__ float red[4 * 5120];   // 80 KB; [0,2560) doubles as prep stage

    const int tid  = threadIdx.x;
    const int lane = tid & 63;
    const int wv   = tid >> 6;
    const int bl   = lane & 15;
    const int g    = lane >> 4;
    const int u    = blockIdx.x;
    const int xcd  = u & 7, sblk = u >> 3;
    const int ib   = xcd * 8 + (sblk & 7);
    const int bg   = sblk >> 3;

    // ---- phase P: prep chunks [9u, 9u+9) ----
    for (int cc = 0; cc < 9; ++cc) {
        const int c = u * 9 + cc;
#pragma unroll
        for (int r = 0; r < 5; ++r) {
            const int idx = r * 512 + tid;   // [o][iloc*128+d*8+k]
            red[idx] = w[(long)(idx >> 8) * (I_ * 128) + (long)c * 256 + (idx & 255)];
        }
        __syncthreads();
        _Float16* dst = pw + (long)c * CHH;
#pragma unroll
        for (int kk = 0; kk < 3; ++kk) {
            const int sidx = kk * 512 + tid;
            if (sidx < 1280) {
                const int hg   = sidx & 1;
                const int ln   = (sidx >> 1) & 63;
                const int pi   = sidx >> 7;
                const int p    = pi % 5;
                const int img  = pi / 5;
                const int r = ln & 15, gg = ln >> 4;
                const int o = 2 * p + hg;
                f16x4 val;
                if (img == 1) {   // P: row r=d, cols n=gg*4+j (sigma)
                    const float4 gv = *(const float4*)&red[o * 256 + (gg & 1) * 128 + r * 8 + (gg >> 1) * 4];
                    val = pack4(gv.x, gv.y, gv.z, gv.w);
                } else {          // Wt: row m=r (sigma), cols d=gg*4+j
                    const int bofs = o * 256 + ((r >> 2) & 1) * 128 + (r >> 3) * 4 + (r & 3);
                    val = pack4(red[bofs + (gg * 4 + 0) * 8], red[bofs + (gg * 4 + 1) * 8],
                                red[bofs + (gg * 4 + 2) * 8], red[bofs + (gg * 4 + 3) * 8]);
                }
                *(f16x4*)(dst + (long)sidx * 4) = val;
            }
        }
        __syncthreads();
    }

    gbar(bar, bar + 1);
    pass_phase<0>(x, pw, v_buf, parts, red, lane, wv, bl, g, ib, bg);
    gbar(bar, bar + 1);
    reduce_phase(parts, v_buf, out, 0.3f, 0.1f, 0, u, lane, wv);
    gbar(bar, bar + 1);
    pass_phase<1>(x, pw, v_buf, parts, red, lane, wv, bl, g, ib, bg);
    gbar(bar, bar + 1);
    reduce_phase(parts, v_buf, out, 0.3f, 1.0f, 1, u, lane, wv);
    gbar(bar, bar + 1);
    pass_phase<1>(x, pw, v_buf, parts, red, lane, wv, bl, g, ib, bg);
    gbar(bar, bar + 1);
    reduce_phase(parts, v_buf, out, 0.4f, 1.0f, 2, u, lane, wv);
}

// ---------------------------------------------------------------------------
extern "C" void kernel_launch(void* const* d_in, const int* in_sizes, int n_in,
                              void* d_out, int out_size, void* d_ws, size_t ws_size,
                              hipStream_t stream)
{
    const float* x = (const float*)d_in[0];   // [128,4608,8]
    const float* w = (const float*)d_in[1];   // [10,4608,16,8]
    float* out   = (float*)d_out;             // [128,10,16]
    float* parts = (float*)d_ws;                          // 5.24 MB
    float* v_buf = parts + (long)NIB * PSET;              // 80 KB
    _Float16* pw = (_Float16*)(v_buf + B_ * O_ * D_);     // 23.6 MB frag images
    unsigned* bar = (unsigned*)((char*)d_ws + (30l << 20));  // barrier state

    hipMemsetAsync(bar, 0, 64, stream);
    cap_kernel<<<NBLKS, 512, 0, stream>>>(x, w, parts, v_buf, out, pw, bar);
}

// Round 8
// 71.221 us; speedup vs baseline: 4.1861x; 4.1861x over previous
//
#include <hip/hip_runtime.h>

#define B_    128
#define I_    4608
#define O_    10
#define D_    16
#define NCHUNKS 2304      // I_/2
#define NIB   64          // i-blocks; 72 i = 36 chunks each
#define CPB   36          // chunks per i-block
#define CHH   5120        // halves per prepped chunk: 2 img * 5 p * 64 lane * 8
#define PSET  20480       // floats per partial set (128*10*16)

typedef _Float16 f16x2 __attribute__((ext_vector_type(2)));
typedef _Float16 f16x4 __attribute__((ext_vector_type(4)));
typedef _Float16 f16x8 __attribute__((ext_vector_type(8)));
typedef float    f32x4 __attribute__((ext_vector_type(4)));
typedef __fp16   pk16x2 __attribute__((ext_vector_type(2)));
typedef unsigned int uint2v __attribute__((ext_vector_type(2)));

__device__ __forceinline__ f16x4 pack4(float a, float b, float c, float d) {
    union { f16x4 v; pk16x2 p[2]; } u;
    u.p[0] = __builtin_amdgcn_cvt_pkrtz(a, b);
    u.p[1] = __builtin_amdgcn_cvt_pkrtz(c, d);
    return u.v;
}
__device__ __forceinline__ f16x2 splat_h2(float a) {
    union { f16x2 v; pk16x2 p; } u;
    u.p = __builtin_amdgcn_cvt_pkrtz(a, a);
    return u.v;
}

// ---------------------------------------------------------------------------
// Prep: W [10][4608][16][8] fp32 -> pre-fragmented f16 images, lane-major:
// pw[chunk][img][p][lane][8 halves]. img0 = Wt (u-GEMM A), img1 = P (apply A).
// sigma: row/col n -> (iloc=(n>>2)&1, k=(n>>3)*4+(n&3)).  (R6-verified)
// ---------------------------------------------------------------------------
__global__ __launch_bounds__(256)
void prep_kernel(const float* __restrict__ w, _Float16* __restrict__ pw)
{
    __shared__ float wch[2560];           // [o][iloc*128 + d*8 + k]
    const int c = blockIdx.x, t = threadIdx.x;
#pragma unroll
    for (int o = 0; o < O_; ++o)
        wch[o * 256 + t] = w[(long)o * (I_ * 128) + (long)c * 256 + t];
    __syncthreads();

    _Float16* dst = pw + (long)c * CHH;
#pragma unroll
    for (int kk = 0; kk < 5; ++kk) {
        const int sidx = t + kk * 256;            // 0..1279 f16x4 slots
        const int hg   = sidx & 1;
        const int lane = (sidx >> 1) & 63;
        const int pi   = sidx >> 7;               // 0..9
        const int p    = pi % 5;
        const int img  = pi / 5;
        const int r = lane & 15, g = lane >> 4;
        const int o = 2 * p + hg;
        f16x4 val;
        if (img == 1) {   // P: row r=d, cols n=g*4+j -> (iloc=g&1, k=(g>>1)*4+j)
            const float4 gg = *(const float4*)&wch[o * 256 + (g & 1) * 128 + r * 8 + (g >> 1) * 4];
            val = pack4(gg.x, gg.y, gg.z, gg.w);
        } else {          // Wt: row m=r (sigma), cols d=g*4+j
            const int bofs = o * 256 + ((r >> 2) & 1) * 128 + (r >> 3) * 4 + (r & 3);
            val = pack4(wch[bofs + (g * 4 + 0) * 8], wch[bofs + (g * 4 + 1) * 8],
                        wch[bofs + (g * 4 + 2) * 8], wch[bofs + (g * 4 + 3) * 8]);
        }
        *(f16x4*)(dst + (long)sidx * 4) = val;
    }
}

// ---------------------------------------------------------------------------
// MFMA routing pass, LDS-free main loop. Grid 512 = 64 i-blocks x 8 b-groups
// (16 b's each), XCD-grouped. 2 blocks/CU (40KB LDS, <=128 VGPR) -> 16
// waves/CU for latency hiding. Each wave independently processes chunks
// c0+wv+8t; frags direct from global (coalesced, register-pipelined).
// End: 3-step LDS tree over waves. MODE 0: uniform c (pre=0.1 in reduce).
// ---------------------------------------------------------------------------
template<int MODE>
__global__ __launch_bounds__(512, 4)
void pass_kernel(const float* __restrict__ x,      // [128][4608][8]
                 const _Float16* __restrict__ pw,  // prepped frag images
                 const float* __restrict__ v,      // [128][10][16]
                 float* __restrict__ parts)        // [NIB][128][10][16]
{
    __shared__ float red[4 * 2560];   // 40 KB

    const int tid  = threadIdx.x;
    const int lane = tid & 63;
    const int wv   = tid >> 6;
    const int bl   = lane & 15;
    const int g    = lane >> 4;
    const int u    = blockIdx.x;
    const int xcd  = u & 7, s = u >> 3;            // s: 0..63
    const int ib   = xcd * 8 + (s & 7);            // same-XCD blocks share ib range
    const int bg   = s >> 3;                       // 0..7
    const int c0   = ib * CPB;
    const int cend = c0 + CPB;
    const int iloc = g & 1, kq = g >> 1;
    const int b0   = bg * 16 + bl;

    f16x4 vf[O_];
    if (MODE == 1) {
#pragma unroll
        for (int o = 0; o < O_; ++o) {
            const float4 vv = *(const float4*)(v + ((long)b0 * O_ + o) * D_ + g * 4);
            vf[o] = pack4(vv.x, vv.y, vv.z, vv.w);
        }
    }

    f32x4 S[O_];
#pragma unroll
    for (int o = 0; o < O_; ++o) S[o] = (f32x4)(0.f);

    const long lofs = (long)lane * 8;
    auto fragp = [&](int c, int img, int p) {
        return (const f16x8*)(pw + (long)c * CHH + img * 2560 + p * 512 + lofs);
    };
    auto xp = [&](int c) {
        return (const float4*)(x + ((long)b0 * I_ + 2 * c + iloc) * 8 + kq * 4);
    };

    int c = c0 + wv;
    f16x8 f0[5], f1[5];
    float4 xqC, xqN;
    if (MODE == 1) {
#pragma unroll
        for (int p = 0; p < 5; ++p) f0[p] = *fragp(c, 0, p);
    }
#pragma unroll
    for (int p = 0; p < 5; ++p) f1[p] = *fragp(c, 1, p);
    xqC = *xp(c);

#pragma unroll
    for (int t5 = 0; t5 < 5; ++t5) {
        const bool valid = (c < cend);
        int cn = c + 8; if (cn > NCHUNKS - 1) cn = NCHUNKS - 1;
        if (valid) {
            xqN = *xp(cn);

            float cs[O_];
            if (MODE == 1) {
                // logits: u = Wt-frag x v ; bd = sum_k u*x
#pragma unroll
                for (int p = 0; p < 5; ++p) {
                    f16x4 ae, ao;
                    ae[0]=f0[p][0]; ae[1]=f0[p][1]; ae[2]=f0[p][2]; ae[3]=f0[p][3];
                    ao[0]=f0[p][4]; ao[1]=f0[p][5]; ao[2]=f0[p][6]; ao[3]=f0[p][7];
                    const f32x4 ua = __builtin_amdgcn_mfma_f32_16x16x16f16(ae, vf[2*p],   (f32x4)(0.f), 0, 0, 0);
                    const f32x4 ub = __builtin_amdgcn_mfma_f32_16x16x16f16(ao, vf[2*p+1], (f32x4)(0.f), 0, 0, 0);
                    float d0 = ua[0] * xqC.x; d0 = fmaf(ua[1], xqC.y, d0);
                    d0 = fmaf(ua[2], xqC.z, d0); d0 = fmaf(ua[3], xqC.w, d0);
                    float d1 = ub[0] * xqC.x; d1 = fmaf(ub[1], xqC.y, d1);
                    d1 = fmaf(ub[2], xqC.z, d1); d1 = fmaf(ub[3], xqC.w, d1);
                    cs[2*p] = d0; cs[2*p+1] = d1;
                }
#pragma unroll
                for (int p = 0; p < 5; ++p) f0[p] = *fragp(cn, 0, p);
                float ssum = 0.f;
#pragma unroll
                for (int o = 0; o < O_; ++o) {
                    const unsigned int tt = __float_as_uint(cs[o]);
                    const uint2v sw = __builtin_amdgcn_permlane32_swap(tt, tt, false, false);
                    const float e = __expf(__uint_as_float(sw[0]) + __uint_as_float(sw[1]));
                    cs[o] = e; ssum += e;
                }
                const float inv = 1.f / ssum;
#pragma unroll
                for (int o = 0; o < O_; ++o) cs[o] *= inv;
            }

            union F4 { f16x4 v; f16x2 h[2]; };
            F4 xh;
            xh.v = pack4(xqC.x, xqC.y, xqC.z, xqC.w);
#pragma unroll
            for (int p = 0; p < 5; ++p) {
                f16x4 pe, po;
                pe[0]=f1[p][0]; pe[1]=f1[p][1]; pe[2]=f1[p][2]; pe[3]=f1[p][3];
                po[0]=f1[p][4]; po[1]=f1[p][5]; po[2]=f1[p][6]; po[3]=f1[p][7];
                F4 ye, yo;
                if (MODE == 0) { ye = xh; yo = xh; }
                else {
                    const f16x2 ce = splat_h2(cs[2*p]);
                    const f16x2 co = splat_h2(cs[2*p+1]);
                    ye.h[0] = xh.h[0] * ce; ye.h[1] = xh.h[1] * ce;
                    yo.h[0] = xh.h[0] * co; yo.h[1] = xh.h[1] * co;
                }
                S[2*p]   = __builtin_amdgcn_mfma_f32_16x16x16f16(pe, ye.v, S[2*p],   0, 0, 0);
                S[2*p+1] = __builtin_amdgcn_mfma_f32_16x16x16f16(po, yo.v, S[2*p+1], 0, 0, 0);
            }
#pragma unroll
            for (int p = 0; p < 5; ++p) f1[p] = *fragp(cn, 1, p);
            xqC = xqN;
        }
        c += 8;
    }

    // ---- inter-wave tree reduction (waves covered disjoint chunks) ----
    auto slot = [&](int w, int o) {
        return &red[w * 2560 + o * 256 + lane * 4];
    };
#define TREE_WR(WSRC)                                                       \
    if (wv >= WSRC && wv < 2 * WSRC) {                                      \
        _Pragma("unroll") for (int o = 0; o < O_; ++o)                      \
            *(f32x4*)slot(wv - WSRC, o) = S[o];                             \
    }                                                                       \
    __syncthreads();                                                        \
    if (wv < WSRC) {                                                        \
        _Pragma("unroll") for (int o = 0; o < O_; ++o)                      \
            S[o] += *(f32x4*)slot(wv, o);                                   \
    }                                                                       \
    __syncthreads();

    TREE_WR(4)
    TREE_WR(2)
    TREE_WR(1)
#undef TREE_WR

    if (wv == 0) {
#pragma unroll
        for (int o = 0; o < O_; ++o) {
            float* pp = parts + (long)ib * PSET + ((long)b0 * O_ + o) * D_ + g * 4;
            *(f32x4*)pp = S[o];
        }
    }
}

// ---------------------------------------------------------------------------
// Reduce 64 partial sets -> s[b,o,d]; squash over d; update v_buf / out.
// Grid 1280 (one block per (b,o)).  (R6-verified)
// ---------------------------------------------------------------------------
__global__ __launch_bounds__(256)
void reduce_squash(const float* __restrict__ parts, float* __restrict__ v_buf,
                   float* __restrict__ out, float kscale, float pre, int mode)
{
    __shared__ float red2[4][16];
    const int tid  = threadIdx.x;
    const int lane = tid & 63;
    const int wv   = tid >> 6;
    const int g2   = blockIdx.x;        // (b*O + o)
    const int pg   = tid >> 4;          // 0..15
    const int d    = tid & 15;

    float s = 0.f;
#pragma unroll
    for (int k = 0; k < 4; ++k)
        s += parts[(long)(pg * 4 + k) * PSET + g2 * D_ + d];

    s += __shfl_xor(s, 16);
    s += __shfl_xor(s, 32);
    if (lane < 16) red2[wv][lane] = s;
    __syncthreads();

    if (tid < 16) {
        float tot = (red2[0][tid] + red2[1][tid]) + (red2[2][tid] + red2[3][tid]);
        tot *= pre;
        float n2 = tot * tot;
        n2 += __shfl_xor(n2, 1);
        n2 += __shfl_xor(n2, 2);
        n2 += __shfl_xor(n2, 4);
        n2 += __shfl_xor(n2, 8);
        const float n     = sqrtf(n2);
        const float scale = n2 / ((1.f + n2) * (n + 1e-8f));
        const float o_    = scale * tot;
        const int idx = g2 * D_ + tid;
        if (mode == 0)      { v_buf[idx] = o_;  out[idx]  = kscale * o_; }
        else if (mode == 1) { v_buf[idx] += o_; out[idx] += kscale * o_; }
        else                {                   out[idx] += kscale * o_; }
    }
}

// ---------------------------------------------------------------------------
extern "C" void kernel_launch(void* const* d_in, const int* in_sizes, int n_in,
                              void* d_out, int out_size, void* d_ws, size_t ws_size,
                              hipStream_t stream)
{
    const float* x = (const float*)d_in[0];   // [128,4608,8]
    const float* w = (const float*)d_in[1];   // [10,4608,16,8]
    float* out   = (float*)d_out;             // [128,10,16]
    float* parts = (float*)d_ws;                          // 64*80KB = 5.24 MB
    float* v_buf = parts + (long)NIB * PSET;              // 80 KB
    _Float16* pw = (_Float16*)(v_buf + B_ * O_ * D_);     // 23.6 MB frag images

    prep_kernel<<<NCHUNKS, 256, 0, stream>>>(w, pw);

    // iter 0: c = 1/10 uniform (folded via pre=0.1)
    pass_kernel<0><<<512, 512, 0, stream>>>(x, pw, v_buf, parts);
    reduce_squash<<<1280, 256, 0, stream>>>(parts, v_buf, out, 0.3f, 0.1f, 0);

    // iter 1: b1 = <out0, xh>
    pass_kernel<1><<<512, 512, 0, stream>>>(x, pw, v_buf, parts);
    reduce_squash<<<1280, 256, 0, stream>>>(parts, v_buf, out, 0.3f, 1.0f, 1);

    // iter 2: b2 = <out0 + out1, xh>
    pass_kernel<1><<<512, 512, 0, stream>>>(x, pw, v_buf, parts);
    reduce_squash<<<1280, 256, 0, stream>>>(parts, v_buf, out, 0.4f, 1.0f, 2);
}